// Round 1
// baseline (3913.987 us; speedup 1.0000x reference)
//
#include <hip/hip_runtime.h>
#include <hip/hip_bf16.h>

// Problem constants
static constexpr int kL  = 5;      // levels
static constexpr int kNH = 4;      // heads
static constexpr int kP  = 4;      // points
static constexpr int kE  = 256;    // embed dims
static constexpr int kC  = 256;    // bev dims
static constexpr int kH  = 128;
static constexpr int kW  = 128;
static constexpr int kNQ = kH * kW;          // 16384
static constexpr int kHD = kE / kNH;         // 64
static constexpr int kNL = 6;
static constexpr int kFF = 2 * kE;           // 512

// ---------------------------------------------------------------------------
// LN over channels of feat_bev: stats pass. feat layout [L, C, nq]
// one thread per (l, n); reads stride nq (coalesced across threads).
// ---------------------------------------------------------------------------
__global__ __launch_bounds__(256) void ln_stats_kernel(
    const float* __restrict__ feat, float* __restrict__ mean_out,
    float* __restrict__ rstd_out) {
  int i = blockIdx.x * 256 + threadIdx.x;        // over L*nq
  int l = i >> 14;                               // / 16384
  int n = i & (kNQ - 1);
  const float* base = feat + (long)l * kC * kNQ + n;
  float s = 0.f, s2 = 0.f;
  for (int c = 0; c < kC; ++c) {
    float v = base[(long)c * kNQ];
    s += v; s2 += v * v;
  }
  float m = s * (1.f / kC);
  float var = s2 * (1.f / kC) - m * m;
  mean_out[i] = m;
  rstd_out[i] = rsqrtf(var + 1e-5f);
}

// ---------------------------------------------------------------------------
// LN apply + transpose: feat [L, C, nq] -> f [L, nq, C]
// grid (C/32, nq/32, L), block 256
// ---------------------------------------------------------------------------
__global__ __launch_bounds__(256) void ln_apply_kernel(
    const float* __restrict__ feat, const float* __restrict__ mean_in,
    const float* __restrict__ rstd_in, const float* __restrict__ g,
    const float* __restrict__ b, float* __restrict__ f) {
  __shared__ float tile[32][33];
  int l  = blockIdx.z;
  int cb = blockIdx.x * 32, nb = blockIdx.y * 32;
  int tx = threadIdx.x & 31;
  int ty = threadIdx.x >> 5;   // 0..7
#pragma unroll
  for (int j = 0; j < 4; ++j) {
    int c = ty + j * 8;
    tile[c][tx] = feat[((long)(l * kC + cb + c)) * kNQ + nb + tx];
  }
  __syncthreads();
#pragma unroll
  for (int j = 0; j < 4; ++j) {
    int nl = ty + j * 8;                  // local n
    int n  = nb + nl;
    float m  = mean_in[l * kNQ + n];
    float rs = rstd_in[l * kNQ + n];
    int c = cb + tx;
    float v = (tile[tx][nl] - m) * rs * g[l * kC + c] + b[l * kC + c];
    f[((long)l * kNQ + n) * kC + c] = v;
  }
}

// ---------------------------------------------------------------------------
// positional encoding: pos[n, e] = e<128 ? pos_col[w][e] : pos_row[h][e-128]
// ---------------------------------------------------------------------------
__global__ __launch_bounds__(256) void pos_kernel(
    const float* __restrict__ pos_row, const float* __restrict__ pos_col,
    float* __restrict__ pos) {
  int idx = blockIdx.x * 256 + threadIdx.x;     // over nq*E
  int n = idx >> 8;
  int e = idx & 255;
  int w = n & (kW - 1);
  int h = n >> 7;
  float v = (e < 128) ? pos_col[w * 128 + e] : pos_row[h * 128 + (e - 128)];
  pos[idx] = v;
}

// ---------------------------------------------------------------------------
// Generic fp32 tiled GEMM: C[z] = sum_b (A[z,b] (+A2)) @ B[b] + bias, act
// A row-major [M,K] lda; B row-major [K,N] ldb; tiles 64x64x16, 256 thr.
// nbatch: accumulate-over-K batches (stride sAb/sBb).
// blockIdx.z: independent batch (stride sAz on A, sCz on C).
// ---------------------------------------------------------------------------
__global__ __launch_bounds__(256) void gemm_kernel(
    const float* __restrict__ A, const float* __restrict__ A2, int lda,
    long sAb, const float* __restrict__ B, int ldb, long sBb, int nbatch,
    const float* __restrict__ bias, float* __restrict__ C, int ldc,
    int N, int K, int act, long sAz, long sCz) {
  __shared__ float As[16][64];
  __shared__ float Bs[16][68];
  int tid = threadIdx.x;
  int col0 = blockIdx.x * 64;
  int row0 = blockIdx.y * 64;
  const float* Az = A + (long)blockIdx.z * sAz;
  float* Cz = C + (long)blockIdx.z * sCz;
  int tx = tid & 15, ty = tid >> 4;
  float acc[4][4] = {};
  for (int bb = 0; bb < nbatch; ++bb) {
    const float* Ab = Az + (long)bb * sAb;
    const float* Bb = B + (long)bb * sBb;
    for (int k0 = 0; k0 < K; k0 += 16) {
      // A tile load: row = tid>>2 (0..63), k = (tid&3)*4
      {
        int r = tid >> 2;
        int kk = (tid & 3) * 4;
        const float* p = Ab + (long)(row0 + r) * lda + k0 + kk;
        float4 v = *(const float4*)p;
        if (A2) {
          const float4 v2 = *(const float4*)(A2 + (long)(row0 + r) * lda + k0 + kk);
          v.x += v2.x; v.y += v2.y; v.z += v2.z; v.w += v2.w;
        }
        As[kk + 0][r] = v.x; As[kk + 1][r] = v.y;
        As[kk + 2][r] = v.z; As[kk + 3][r] = v.w;
      }
      // B tile load: k = tid>>4 (0..15), n = (tid&15)*4
      {
        int kk = tid >> 4;
        int c = (tid & 15) * 4;
        const float* p = Bb + (long)(k0 + kk) * ldb + col0 + c;
#pragma unroll
        for (int j = 0; j < 4; ++j) {
          int cc = col0 + c + j;
          Bs[kk][c + j] = (cc < N) ? p[j] : 0.f;
        }
      }
      __syncthreads();
#pragma unroll
      for (int k = 0; k < 16; ++k) {
        float a[4], bv[4];
#pragma unroll
        for (int i = 0; i < 4; ++i) a[i] = As[k][ty * 4 + i];
#pragma unroll
        for (int j = 0; j < 4; ++j) bv[j] = Bs[k][tx * 4 + j];
#pragma unroll
        for (int i = 0; i < 4; ++i)
#pragma unroll
          for (int j = 0; j < 4; ++j) acc[i][j] += a[i] * bv[j];
      }
      __syncthreads();
    }
  }
#pragma unroll
  for (int i = 0; i < 4; ++i) {
    int r = row0 + ty * 4 + i;
#pragma unroll
    for (int j = 0; j < 4; ++j) {
      int cc = col0 + tx * 4 + j;
      if (cc < N) {
        float v = acc[i][j] + (bias ? bias[cc] : 0.f);
        if (act == 1) v = fmaxf(v, 0.f);
        Cz[(long)r * ldc + cc] = v;
      }
    }
  }
}

// ---------------------------------------------------------------------------
// softmax over 20 (L*P) per (n, head). aw in-place, layout [nq, 80]
// ---------------------------------------------------------------------------
__global__ __launch_bounds__(256) void softmax_kernel(float* __restrict__ aw) {
  int i = blockIdx.x * 256 + threadIdx.x;       // (n,h)
  int n = i >> 2, h = i & 3;
  float* p = aw + (long)n * 80 + h * 20;
  float v[20];
  float mx = -1e30f;
#pragma unroll
  for (int j = 0; j < 20; ++j) { v[j] = p[j]; mx = fmaxf(mx, v[j]); }
  float s = 0.f;
#pragma unroll
  for (int j = 0; j < 20; ++j) { v[j] = __expf(v[j] - mx); s += v[j]; }
  float inv = 1.f / s;
#pragma unroll
  for (int j = 0; j < 20; ++j) p[j] = v[j] * inv;
}

// ---------------------------------------------------------------------------
// Deformable sampling: one wave per (n, head), lane = channel d (0..63).
// off [nq,160] (h*40 + (l*4+p)*2 + xy), aw [nq,80] softmaxed,
// val [L, nq, E] (e = h*64+d)  ->  acc [nq, E]
// ---------------------------------------------------------------------------
__global__ __launch_bounds__(256) void sample_kernel(
    const float* __restrict__ off, const float* __restrict__ aw,
    const float* __restrict__ val, float* __restrict__ accb) {
  int pair = blockIdx.x * 4 + (threadIdx.x >> 6);
  int lane = threadIdx.x & 63;
  int n = pair >> 2, h = pair & 3;
  int wq = n & (kW - 1);
  int hq = n >> 7;
  const float* offp = off + (long)n * 160 + h * 40;
  const float* awp  = aw + (long)n * 80 + h * 20;
  float a = 0.f;
  for (int l = 0; l < kL; ++l) {
    const float* vbase = val + (long)l * kNQ * kE + h * 64 + lane;
#pragma unroll
    for (int p = 0; p < kP; ++p) {
      float ox = offp[(l * 4 + p) * 2 + 0];
      float oy = offp[(l * 4 + p) * 2 + 1];
      float w_att = awp[l * 4 + p];
      float x = (float)wq + ox;       // loc_x*W - 0.5 simplifies to w + off_x
      float y = (float)hq + oy;
      float x0f = floorf(x), y0f = floorf(y);
      float fx = x - x0f, fy = y - y0f;
      int x0 = (int)x0f, y0 = (int)y0f;
#pragma unroll
      for (int cidx = 0; cidx < 4; ++cidx) {
        int dx = cidx & 1, dy = cidx >> 1;
        int ix = x0 + dx, iy = y0 + dy;
        float wgt = (dx ? fx : 1.f - fx) * (dy ? fy : 1.f - fy);
        bool valid = (ix >= 0 && ix < kW && iy >= 0 && iy < kH);
        int cix = min(max(ix, 0), kW - 1);
        int ciy = min(max(iy, 0), kH - 1);
        int sidx = ciy * kW + cix;
        float coef = valid ? w_att * wgt : 0.f;
        a += coef * vbase[(long)sidx * kE];
      }
    }
  }
  accb[(long)n * kE + h * 64 + lane] = a;
}

// ---------------------------------------------------------------------------
// q = LayerNorm(a + r) * g + b   — one wave per row of 256
// ---------------------------------------------------------------------------
__global__ __launch_bounds__(256) void ln_res_kernel(
    const float* __restrict__ a, const float* __restrict__ r,
    const float* __restrict__ g, const float* __restrict__ b,
    float* __restrict__ out) {
  int wave = threadIdx.x >> 6;
  int lane = threadIdx.x & 63;
  long row = (long)blockIdx.x * 4 + wave;
  float4 va = ((const float4*)(a + row * kE))[lane];
  float4 vr = ((const float4*)(r + row * kE))[lane];
  float x0 = va.x + vr.x, x1 = va.y + vr.y, x2 = va.z + vr.z, x3 = va.w + vr.w;
  float s  = x0 + x1 + x2 + x3;
  float s2 = x0 * x0 + x1 * x1 + x2 * x2 + x3 * x3;
#pragma unroll
  for (int o = 32; o > 0; o >>= 1) {
    s  += __shfl_down(s, o);
    s2 += __shfl_down(s2, o);
  }
  s = __shfl(s, 0); s2 = __shfl(s2, 0);
  float m  = s * (1.f / kE);
  float var = s2 * (1.f / kE) - m * m;
  float rs = rsqrtf(var + 1e-5f);
  float4 vg = ((const float4*)g)[lane];
  float4 vb = ((const float4*)b)[lane];
  float4 o;
  o.x = (x0 - m) * rs * vg.x + vb.x;
  o.y = (x1 - m) * rs * vg.y + vb.y;
  o.z = (x2 - m) * rs * vg.z + vb.z;
  o.w = (x3 - m) * rs * vg.w + vb.w;
  ((float4*)(out + row * kE))[lane] = o;
}

// ---------------------------------------------------------------------------
// final transpose: out[e, n] = q[n, e]
// ---------------------------------------------------------------------------
__global__ __launch_bounds__(256) void transpose_kernel(
    const float* __restrict__ q, float* __restrict__ out) {
  __shared__ float t[32][33];
  int eb = blockIdx.x * 32, nb = blockIdx.y * 32;
  int tx = threadIdx.x & 31, ty = threadIdx.x >> 5;
#pragma unroll
  for (int j = 0; j < 4; ++j)
    t[ty + j * 8][tx] = q[(long)(nb + ty + j * 8) * kE + eb + tx];
  __syncthreads();
#pragma unroll
  for (int j = 0; j < 4; ++j)
    out[(long)(eb + ty + j * 8) * kNQ + nb + tx] = t[tx][ty + j * 8];
}

// ---------------------------------------------------------------------------
static inline void gemm(hipStream_t s, const float* A, const float* A2, int lda,
                        long sAb, int nbatch, const float* B, int ldb, long sBb,
                        const float* bias, float* C, int ldc, int M, int N,
                        int K, int act, int nz = 1, long sAz = 0, long sCz = 0) {
  dim3 grid((N + 63) / 64, M / 64, nz);
  gemm_kernel<<<grid, 256, 0, s>>>(A, A2, lda, sAb, B, ldb, sBb, nbatch, bias,
                                   C, ldc, N, K, act, sAz, sCz);
}

extern "C" void kernel_launch(void* const* d_in, const int* in_sizes, int n_in,
                              void* d_out, int out_size, void* d_ws,
                              size_t ws_size, hipStream_t stream) {
  const float* feat    = (const float*)d_in[0];
  const float* norm0_g = (const float*)d_in[1];
  const float* norm0_b = (const float*)d_in[2];
  const float* in_w    = (const float*)d_in[3];
  const float* in_b    = (const float*)d_in[4];
  const float* pos_row = (const float*)d_in[5];
  const float* pos_col = (const float*)d_in[6];
  const float* off_w   = (const float*)d_in[7];
  const float* off_b   = (const float*)d_in[8];
  const float* aw_w    = (const float*)d_in[9];
  const float* aw_b    = (const float*)d_in[10];
  const float* val_w   = (const float*)d_in[11];
  const float* val_b   = (const float*)d_in[12];
  const float* out_w   = (const float*)d_in[13];
  const float* out_b   = (const float*)d_in[14];
  const float* ln1_g   = (const float*)d_in[15];
  const float* ln1_b   = (const float*)d_in[16];
  const float* ln2_g   = (const float*)d_in[17];
  const float* ln2_b   = (const float*)d_in[18];
  const float* ffn_w1  = (const float*)d_in[19];
  const float* ffn_b1  = (const float*)d_in[20];
  const float* ffn_w2  = (const float*)d_in[21];
  const float* ffn_b2  = (const float*)d_in[22];

  float* ws = (float*)d_ws;
  float* f       = ws; ws += (size_t)kL * kNQ * kC;   // 20.97M
  float* val     = ws; ws += (size_t)kL * kNQ * kE;   // 20.97M
  float* posb    = ws; ws += (size_t)kNQ * kE;
  float* q       = ws; ws += (size_t)kNQ * kE;
  float* tmp     = ws; ws += (size_t)kNQ * kE;
  float* accb    = ws; ws += (size_t)kNQ * kE;
  float* hid     = ws; ws += (size_t)kNQ * kFF;
  float* off_raw = ws; ws += (size_t)kNQ * 160;
  float* aw_buf  = ws; ws += (size_t)kNQ * 80;
  float* meanb   = ws; ws += (size_t)kL * kNQ;
  float* rstdb   = ws; ws += (size_t)kL * kNQ;

  // --- precompute ---
  ln_stats_kernel<<<kL * kNQ / 256, 256, 0, stream>>>(feat, meanb, rstdb);
  ln_apply_kernel<<<dim3(kC / 32, kNQ / 32, kL), 256, 0, stream>>>(
      feat, meanb, rstdb, norm0_g, norm0_b, f);
  pos_kernel<<<kNQ * kE / 256, 256, 0, stream>>>(pos_row, pos_col, posb);
  // input proj: q = sum_l f[l] @ in_w[l] + in_b
  gemm(stream, f, nullptr, kC, (long)kNQ * kC, kL, in_w, kE, (long)kC * kE,
       in_b, q, kE, kNQ, kE, kC, 0);

  for (int i = 0; i < kNL; ++i) {
    const float* off_w_i = off_w + (long)i * kE * 160;
    const float* off_b_i = off_b + (long)i * 160;
    const float* aw_w_i  = aw_w + (long)i * kE * 80;
    const float* aw_b_i  = aw_b + (long)i * 80;
    const float* val_w_i = val_w + (long)i * kC * kE;
    const float* val_b_i = val_b + (long)i * kE;
    const float* out_w_i = out_w + (long)i * kE * kE;
    const float* out_b_i = out_b + (long)i * kE;
    const float* w1_i = ffn_w1 + (long)i * kE * kFF;
    const float* b1_i = ffn_b1 + (long)i * kFF;
    const float* w2_i = ffn_w2 + (long)i * kFF * kE;
    const float* b2_i = ffn_b2 + (long)i * kE;

    // off / aw from qp = q + pos
    gemm(stream, q, posb, kE, 0, 1, off_w_i, 160, 0, off_b_i, off_raw, 160,
         kNQ, 160, kE, 0);
    gemm(stream, q, posb, kE, 0, 1, aw_w_i, 80, 0, aw_b_i, aw_buf, 80,
         kNQ, 80, kE, 0);
    softmax_kernel<<<kNQ * kNH / 256, 256, 0, stream>>>(aw_buf);
    // val[l] = f[l] @ val_w[i] + val_b[i]
    gemm(stream, f, nullptr, kC, 0, 1, val_w_i, kE, 0, val_b_i, val, kE,
         kNQ, kE, kC, 0, kL, (long)kNQ * kC, (long)kNQ * kE);
    // deformable sampling
    sample_kernel<<<kNQ * kNH / 4, 256, 0, stream>>>(off_raw, aw_buf, val,
                                                     accb);
    // out proj + residual + LN1
    gemm(stream, accb, nullptr, kE, 0, 1, out_w_i, kE, 0, out_b_i, tmp, kE,
         kNQ, kE, kE, 0);
    ln_res_kernel<<<kNQ / 4, 256, 0, stream>>>(q, tmp, ln1_g + (long)i * kE,
                                               ln1_b + (long)i * kE, q);
    // FFN + residual + LN2
    gemm(stream, q, nullptr, kE, 0, 1, w1_i, kFF, 0, b1_i, hid, kFF, kNQ, kFF,
         kE, 1);
    gemm(stream, hid, nullptr, kFF, 0, 1, w2_i, kE, 0, b2_i, tmp, kE, kNQ, kE,
         kFF, 0);
    ln_res_kernel<<<kNQ / 4, 256, 0, stream>>>(q, tmp, ln2_g + (long)i * kE,
                                               ln2_b + (long)i * kE, q);
  }

  transpose_kernel<<<dim3(kE / 32, kNQ / 32), 256, 0, stream>>>(q,
                                                                (float*)d_out);
}

// Round 3
// 1732.756 us; speedup vs baseline: 2.2588x; 2.2588x over previous
//
#include <hip/hip_runtime.h>
#include <hip/hip_bf16.h>
#include <stdint.h>

// Problem constants
static constexpr int kL  = 5;
static constexpr int kNH = 4;
static constexpr int kP  = 4;
static constexpr int kE  = 256;
static constexpr int kC  = 256;
static constexpr int kH  = 128;
static constexpr int kW  = 128;
static constexpr int kNQ = kH * kW;          // 16384
static constexpr int kNL = 6;
static constexpr int kFF = 2 * kE;           // 512
static constexpr int kCOMB = 240;            // 160 off + 80 aw

typedef short bf16x8 __attribute__((ext_vector_type(8)));
typedef float f32x4 __attribute__((ext_vector_type(4)));

__device__ __forceinline__ short f2bf(float x) {
  union { float f; uint32_t u; } v; v.f = x;
  uint32_t r = v.u + 0x7fffu + ((v.u >> 16) & 1u);
  return (short)(r >> 16);
}

__device__ __forceinline__ void gl_lds16(const void* g, void* l) {
  __builtin_amdgcn_global_load_lds(
      (const __attribute__((address_space(1))) void*)g,
      (__attribute__((address_space(3))) void*)l, 16, 0, 0);
}

// ---------------------------------------------------------------------------
// bf16 MFMA GEMM: C = sum_bb A[bb] @ B^T + bias  (B stored transposed [N,K])
// Block tile: 128 rows x BN cols. 4 waves in 2x2 grid:
//   wave (wy,wx) computes rows wy*64..+63, cols wx*(BN/2) + t*16, t<NTW
//   NTW = BN/32  -> full column coverage (2 * 16 * NTW == BN).
// ---------------------------------------------------------------------------
template <int BN>
__global__ __launch_bounds__(256) void mfma_gemm_kernel(
    const short* __restrict__ A, long sAb, int lda,
    const short* __restrict__ BT, int ldbt, int Kb, int nbatch,
    const float* __restrict__ bias,
    float* __restrict__ Cf, short* __restrict__ Cb, int ldc,
    int Nreal, int relu) {
  constexpr int NTW = BN / 32;         // col tiles per wave
  __shared__ short As[128 * 32];
  __shared__ short Bs[BN * 32];
  const int tid = threadIdx.x;
  const int wave = tid >> 6, lane = tid & 63;
  const int wy = wave >> 1, wx = wave & 1;   // 2x2 wave grid
  const long row0 = (long)blockIdx.y * 128;
  const int col0 = blockIdx.x * BN;
  const int srow = lane >> 2;          // 0..15 (row within 16-row chunk)
  const int skof = (lane & 3) * 8;     // element offset within 32-elem k row
  const int fr = lane & 15;
  const int fq = lane >> 4;
  f32x4 acc[4][NTW] = {};
  for (int bb = 0; bb < nbatch; ++bb) {
    const short* Ab = A + (long)bb * sAb + row0 * lda;
    const short* Bb = BT + (long)col0 * ldbt + (long)bb * Kb;
    for (int k0 = 0; k0 < Kb; k0 += 32) {
      __syncthreads();
#pragma unroll
      for (int j = 0; j < 2; ++j) {          // A: 8 insts x 16 rows = 128
        int inst = wave * 2 + j;
        int r = inst * 16 + srow;
        gl_lds16(Ab + (long)r * lda + k0 + skof, &As[inst * 512]);
      }
#pragma unroll
      for (int j = 0; j < BN / 64; ++j) {    // B: BN/16 insts x 16 rows
        int inst = wave * (BN / 64) + j;
        int r = inst * 16 + srow;
        gl_lds16(Bb + (long)r * ldbt + k0 + skof, &Bs[inst * 512]);
      }
      __syncthreads();
      bf16x8 af[4], bfv[NTW];
#pragma unroll
      for (int t = 0; t < 4; ++t)
        af[t] = *(const bf16x8*)&As[(wy * 64 + t * 16 + fr) * 32 + fq * 8];
#pragma unroll
      for (int t = 0; t < NTW; ++t)
        bfv[t] = *(const bf16x8*)&Bs[(wx * (BN / 2) + t * 16 + fr) * 32 + fq * 8];
#pragma unroll
      for (int mt = 0; mt < 4; ++mt)
#pragma unroll
        for (int nt = 0; nt < NTW; ++nt)
          acc[mt][nt] = __builtin_amdgcn_mfma_f32_16x16x32_bf16(
              af[mt], bfv[nt], acc[mt][nt], 0, 0, 0);
    }
  }
  const int ccol0 = col0 + wx * (BN / 2) + fr;
  const long crow0 = row0 + wy * 64 + fq * 4;
#pragma unroll
  for (int nt = 0; nt < NTW; ++nt) {
    int col = ccol0 + nt * 16;
    bool cok = col < Nreal;
    float bv = (cok && bias) ? bias[col] : 0.f;
#pragma unroll
    for (int mt = 0; mt < 4; ++mt) {
#pragma unroll
      for (int r = 0; r < 4; ++r) {
        long row = crow0 + mt * 16 + r;
        float v = acc[mt][nt][r] + bv;
        if (relu) v = fmaxf(v, 0.f);
        if (cok) {
          if (Cf) Cf[row * ldc + col] = v;
          if (Cb) Cb[row * ldc + col] = f2bf(v);
        }
      }
    }
  }
}

// ---------------------------------------------------------------------------
// weight convert+transpose: in fp32 [Z,K,N] -> out bf16 [Z,N,K]
// ---------------------------------------------------------------------------
__global__ __launch_bounds__(256) void wt_convert_kernel(
    const float* __restrict__ in, short* __restrict__ out, int K, int N) {
  long idx = (long)blockIdx.x * 256 + threadIdx.x;  // over N*K
  int z = blockIdx.y;
  int n = (int)(idx / K);
  int k = (int)(idx - (long)n * K);
  out[(long)z * N * K + idx] = f2bf(in[(long)z * K * N + (long)k * N + n]);
}

// off_w [Z,256,160] + aw_w [Z,256,80] -> combT bf16 [Z, 256 rows(n), 256(k)]
// rows 0..159 = off^T, 160..239 = aw^T, 240..255 = 0. Also builds comb bias.
__global__ __launch_bounds__(256) void comb_convert_kernel(
    const float* __restrict__ off_w, const float* __restrict__ aw_w,
    const float* __restrict__ off_b, const float* __restrict__ aw_b,
    short* __restrict__ combT, float* __restrict__ comb_bias) {
  int idx = blockIdx.x * 256 + threadIdx.x;   // 65536 per z
  int z = blockIdx.y;
  int n = idx >> 8, k = idx & 255;
  float v = 0.f;
  if (n < 160) v = off_w[((long)z * 256 + k) * 160 + n];
  else if (n < kCOMB) v = aw_w[((long)z * 256 + k) * 80 + (n - 160)];
  combT[(long)z * 65536 + idx] = f2bf(v);
  if (k == 0)
    comb_bias[z * 256 + n] =
        (n < 160) ? off_b[z * 160 + n]
                  : (n < kCOMB ? aw_b[z * 80 + (n - 160)] : 0.f);
}

// ---------------------------------------------------------------------------
// LN over channels of feat [L, C, nq]: stats
// ---------------------------------------------------------------------------
__global__ __launch_bounds__(256) void ln_stats_kernel(
    const float* __restrict__ feat, float* __restrict__ mean_out,
    float* __restrict__ rstd_out) {
  int i = blockIdx.x * 256 + threadIdx.x;
  int l = i >> 14;
  int n = i & (kNQ - 1);
  const float* base = feat + (long)l * kC * kNQ + n;
  float s = 0.f, s2 = 0.f;
  for (int c = 0; c < kC; ++c) {
    float v = base[(long)c * kNQ];
    s += v; s2 += v * v;
  }
  float m = s * (1.f / kC);
  float var = s2 * (1.f / kC) - m * m;
  mean_out[i] = m;
  rstd_out[i] = rsqrtf(var + 1e-5f);
}

// LN apply + transpose -> f bf16 [L, nq, C]
__global__ __launch_bounds__(256) void ln_apply_kernel(
    const float* __restrict__ feat, const float* __restrict__ mean_in,
    const float* __restrict__ rstd_in, const float* __restrict__ g,
    const float* __restrict__ b, short* __restrict__ f) {
  __shared__ float tile[32][33];
  int l  = blockIdx.z;
  int cb = blockIdx.x * 32, nb = blockIdx.y * 32;
  int tx = threadIdx.x & 31;
  int ty = threadIdx.x >> 5;
#pragma unroll
  for (int j = 0; j < 4; ++j) {
    int c = ty + j * 8;
    tile[c][tx] = feat[((long)(l * kC + cb + c)) * kNQ + nb + tx];
  }
  __syncthreads();
#pragma unroll
  for (int j = 0; j < 4; ++j) {
    int nl = ty + j * 8;
    int n  = nb + nl;
    float m  = mean_in[l * kNQ + n];
    float rs = rstd_in[l * kNQ + n];
    int c = cb + tx;
    float v = (tile[tx][nl] - m) * rs * g[l * kC + c] + b[l * kC + c];
    f[((long)l * kNQ + n) * kC + c] = f2bf(v);
  }
}

// qp = bf16(q + pos) with pos computed on the fly
__global__ __launch_bounds__(256) void qp_kernel(
    const float* __restrict__ q, const float* __restrict__ pos_row,
    const float* __restrict__ pos_col, short* __restrict__ qp) {
  int idx = blockIdx.x * 256 + threadIdx.x;  // over nq*64 (4 elems each)
  int n = idx >> 6;
  int e4 = (idx & 63) * 4;
  int w = n & (kW - 1), h = n >> 7;
  float4 vq = *(const float4*)(q + (long)n * kE + e4);
  float4 vp = (e4 < 128) ? *(const float4*)(pos_col + w * 128 + e4)
                         : *(const float4*)(pos_row + h * 128 + e4 - 128);
  short4 o;
  o.x = f2bf(vq.x + vp.x); o.y = f2bf(vq.y + vp.y);
  o.z = f2bf(vq.z + vp.z); o.w = f2bf(vq.w + vp.w);
  *(short4*)(qp + (long)n * kE + e4) = o;
}

// softmax over 20 per (n, head), in-place in comb[n*240 + 160 + h*20]
__global__ __launch_bounds__(256) void softmax_kernel(float* __restrict__ comb) {
  int i = blockIdx.x * 256 + threadIdx.x;
  int n = i >> 2, h = i & 3;
  float* p = comb + (long)n * kCOMB + 160 + h * 20;
  float v[20];
  float mx = -1e30f;
#pragma unroll
  for (int j = 0; j < 20; ++j) { v[j] = p[j]; mx = fmaxf(mx, v[j]); }
  float s = 0.f;
#pragma unroll
  for (int j = 0; j < 20; ++j) { v[j] = __expf(v[j] - mx); s += v[j]; }
  float inv = 1.f / s;
#pragma unroll
  for (int j = 0; j < 20; ++j) p[j] = v[j] * inv;
}

// deformable sampling; off/aw from comb, val fp32, out accb bf16
__global__ __launch_bounds__(256) void sample_kernel(
    const float* __restrict__ comb, const float* __restrict__ val,
    short* __restrict__ accb) {
  int pair = blockIdx.x * 4 + (threadIdx.x >> 6);
  int lane = threadIdx.x & 63;
  int n = pair >> 2, h = pair & 3;
  int wq = n & (kW - 1);
  int hq = n >> 7;
  const float* offp = comb + (long)n * kCOMB + h * 40;
  const float* awp  = comb + (long)n * kCOMB + 160 + h * 20;
  float a = 0.f;
  for (int l = 0; l < kL; ++l) {
    const float* vbase = val + (long)l * kNQ * kE + h * 64 + lane;
#pragma unroll
    for (int p = 0; p < kP; ++p) {
      float ox = offp[(l * 4 + p) * 2 + 0];
      float oy = offp[(l * 4 + p) * 2 + 1];
      float w_att = awp[l * 4 + p];
      float x = (float)wq + ox;
      float y = (float)hq + oy;
      float x0f = floorf(x), y0f = floorf(y);
      float fx = x - x0f, fy = y - y0f;
      int x0 = (int)x0f, y0 = (int)y0f;
#pragma unroll
      for (int cidx = 0; cidx < 4; ++cidx) {
        int dx = cidx & 1, dy = cidx >> 1;
        int ix = x0 + dx, iy = y0 + dy;
        float wgt = (dx ? fx : 1.f - fx) * (dy ? fy : 1.f - fy);
        bool valid = (ix >= 0 && ix < kW && iy >= 0 && iy < kH);
        int cix = min(max(ix, 0), kW - 1);
        int ciy = min(max(iy, 0), kH - 1);
        int sidx = ciy * kW + cix;
        float coef = valid ? w_att * wgt : 0.f;
        a += coef * vbase[(long)sidx * kE];
      }
    }
  }
  accb[(long)n * kE + h * 64 + lane] = f2bf(a);
}

// q = LayerNorm(a + r) * g + b ; writes fp32 q and bf16 copy
__global__ __launch_bounds__(256) void ln_res_kernel(
    const float* __restrict__ a, const float* __restrict__ r,
    const float* __restrict__ g, const float* __restrict__ b,
    float* __restrict__ out, short* __restrict__ outb) {
  int wave = threadIdx.x >> 6;
  int lane = threadIdx.x & 63;
  long row = (long)blockIdx.x * 4 + wave;
  float4 va = ((const float4*)(a + row * kE))[lane];
  float4 vr = ((const float4*)(r + row * kE))[lane];
  float x0 = va.x + vr.x, x1 = va.y + vr.y, x2 = va.z + vr.z, x3 = va.w + vr.w;
  float s  = x0 + x1 + x2 + x3;
  float s2 = x0 * x0 + x1 * x1 + x2 * x2 + x3 * x3;
#pragma unroll
  for (int o = 32; o > 0; o >>= 1) {
    s  += __shfl_down(s, o);
    s2 += __shfl_down(s2, o);
  }
  s = __shfl(s, 0); s2 = __shfl(s2, 0);
  float m  = s * (1.f / kE);
  float var = s2 * (1.f / kE) - m * m;
  float rs = rsqrtf(var + 1e-5f);
  float4 vg = ((const float4*)g)[lane];
  float4 vb = ((const float4*)b)[lane];
  float4 o;
  o.x = (x0 - m) * rs * vg.x + vb.x;
  o.y = (x1 - m) * rs * vg.y + vb.y;
  o.z = (x2 - m) * rs * vg.z + vb.z;
  o.w = (x3 - m) * rs * vg.w + vb.w;
  ((float4*)(out + row * kE))[lane] = o;
  short4 ob;
  ob.x = f2bf(o.x); ob.y = f2bf(o.y); ob.z = f2bf(o.z); ob.w = f2bf(o.w);
  ((short4*)(outb + row * kE))[lane] = ob;
}

// final transpose: out[e, n] = q[n, e]
__global__ __launch_bounds__(256) void transpose_kernel(
    const float* __restrict__ q, float* __restrict__ out) {
  __shared__ float t[32][33];
  int eb = blockIdx.x * 32, nb = blockIdx.y * 32;
  int tx = threadIdx.x & 31, ty = threadIdx.x >> 5;
#pragma unroll
  for (int j = 0; j < 4; ++j)
    t[ty + j * 8][tx] = q[(long)(nb + ty + j * 8) * kE + eb + tx];
  __syncthreads();
#pragma unroll
  for (int j = 0; j < 4; ++j)
    out[(long)(eb + ty + j * 8) * kNQ + nb + tx] = t[tx][ty + j * 8];
}

// ---------------------------------------------------------------------------
template <int BN>
static inline void mgemm(hipStream_t s, const short* A, long sAb, int lda,
                         const short* BT, int ldbt, int Kb, int nbatch,
                         const float* bias, float* Cf, short* Cb, int ldc,
                         int M, int Ntiles, int Nreal, int relu) {
  mfma_gemm_kernel<BN><<<dim3(Ntiles, M / 128), 256, 0, s>>>(
      A, sAb, lda, BT, ldbt, Kb, nbatch, bias, Cf, Cb, ldc, Nreal, relu);
}

extern "C" void kernel_launch(void* const* d_in, const int* in_sizes, int n_in,
                              void* d_out, int out_size, void* d_ws,
                              size_t ws_size, hipStream_t stream) {
  const float* feat    = (const float*)d_in[0];
  const float* norm0_g = (const float*)d_in[1];
  const float* norm0_b = (const float*)d_in[2];
  const float* in_w    = (const float*)d_in[3];
  const float* in_b    = (const float*)d_in[4];
  const float* pos_row = (const float*)d_in[5];
  const float* pos_col = (const float*)d_in[6];
  const float* off_w   = (const float*)d_in[7];
  const float* off_b   = (const float*)d_in[8];
  const float* aw_w    = (const float*)d_in[9];
  const float* aw_b    = (const float*)d_in[10];
  const float* val_w   = (const float*)d_in[11];
  const float* val_b   = (const float*)d_in[12];
  const float* out_w   = (const float*)d_in[13];
  const float* out_b   = (const float*)d_in[14];
  const float* ln1_g   = (const float*)d_in[15];
  const float* ln1_b   = (const float*)d_in[16];
  const float* ln2_g   = (const float*)d_in[17];
  const float* ln2_b   = (const float*)d_in[18];
  const float* ffn_w1  = (const float*)d_in[19];
  const float* ffn_b1  = (const float*)d_in[20];
  const float* ffn_w2  = (const float*)d_in[21];
  const float* ffn_b2  = (const float*)d_in[22];

  char* p = (char*)d_ws;
  auto alloc = [&](size_t bytes) -> char* {
    char* r = p;
    p += (bytes + 255) & ~(size_t)255;
    return r;
  };
  short* f_bf   = (short*)alloc((size_t)kL * kNQ * kC * 2);
  float* val    = (float*)alloc((size_t)kL * kNQ * kE * 4);
  float* q      = (float*)alloc((size_t)kNQ * kE * 4);
  float* tmp    = (float*)alloc((size_t)kNQ * kE * 4);
  short* qbf    = (short*)alloc((size_t)kNQ * kE * 2);
  short* qp_bf  = (short*)alloc((size_t)kNQ * kE * 2);
  short* accb   = (short*)alloc((size_t)kNQ * kE * 2);
  short* hid_bf = (short*)alloc((size_t)kNQ * kFF * 2);
  float* comb   = (float*)alloc((size_t)kNQ * kCOMB * 4);
  float* comb_b = (float*)alloc((size_t)kNL * 256 * 4);
  float* meanb  = (float*)alloc((size_t)kL * kNQ * 4);
  float* rstdb  = (float*)alloc((size_t)kL * kNQ * 4);
  short* inT    = (short*)alloc((size_t)256 * 1280 * 2);
  short* valT   = (short*)alloc((size_t)kNL * 256 * 256 * 2);
  short* outT   = (short*)alloc((size_t)kNL * 256 * 256 * 2);
  short* ffn1T  = (short*)alloc((size_t)kNL * 512 * 256 * 2);
  short* ffn2T  = (short*)alloc((size_t)kNL * 256 * 512 * 2);
  short* combT  = (short*)alloc((size_t)kNL * 256 * 256 * 2);

  // weight conversions (bf16, transposed to [N,K])
  wt_convert_kernel<<<dim3(1280, 1), 256, 0, stream>>>(in_w, inT, 1280, 256);
  wt_convert_kernel<<<dim3(256, kNL), 256, 0, stream>>>(val_w, valT, 256, 256);
  wt_convert_kernel<<<dim3(256, kNL), 256, 0, stream>>>(out_w, outT, 256, 256);
  wt_convert_kernel<<<dim3(512, kNL), 256, 0, stream>>>(ffn_w1, ffn1T, 256, 512);
  wt_convert_kernel<<<dim3(512, kNL), 256, 0, stream>>>(ffn_w2, ffn2T, 512, 256);
  comb_convert_kernel<<<dim3(256, kNL), 256, 0, stream>>>(off_w, aw_w, off_b,
                                                          aw_b, combT, comb_b);

  // feature LN -> f bf16
  ln_stats_kernel<<<kL * kNQ / 256, 256, 0, stream>>>(feat, meanb, rstdb);
  ln_apply_kernel<<<dim3(kC / 32, kNQ / 32, kL), 256, 0, stream>>>(
      feat, meanb, rstdb, norm0_g, norm0_b, f_bf);

  // input proj: q = sum_l f[l] @ in_w[l] + in_b   (K-batched)
  mgemm<64>(stream, f_bf, (long)kNQ * kC, kC, inT, 1280, 256, kL, in_b, q,
            nullptr, kE, kNQ, 4, kE, 0);

  for (int i = 0; i < kNL; ++i) {
    const short* combT_i = combT + (long)i * 256 * 256;
    const short* valT_i  = valT + (long)i * 256 * 256;
    const short* outT_i  = outT + (long)i * 256 * 256;
    const short* f1T_i   = ffn1T + (long)i * 512 * 256;
    const short* f2T_i   = ffn2T + (long)i * 256 * 512;

    qp_kernel<<<kNQ * 64 / 256, 256, 0, stream>>>(q, pos_row, pos_col, qp_bf);
    // fused off+aw GEMM (N=240, padded BT rows to 256)
    mgemm<64>(stream, qp_bf, 0, kE, combT_i, 256, 256, 1, comb_b + i * 256,
              comb, nullptr, kCOMB, kNQ, 4, kCOMB, 0);
    softmax_kernel<<<kNQ * kNH / 256, 256, 0, stream>>>(comb);
    // val[l] = f[l] @ val_w[i] : one GEMM, M = L*nq
    mgemm<128>(stream, f_bf, 0, kC, valT_i, 256, 256, 1,
               val_b + (long)i * kE, val, nullptr, kE, kL * kNQ, 2, kE, 0);
    sample_kernel<<<kNQ * kNH / 4, 256, 0, stream>>>(comb, val, accb);
    // out proj
    mgemm<64>(stream, accb, 0, kE, outT_i, 256, 256, 1, out_b + (long)i * kE,
              tmp, nullptr, kE, kNQ, 4, kE, 0);
    ln_res_kernel<<<kNQ / 4, 256, 0, stream>>>(q, tmp, ln1_g + (long)i * kE,
                                               ln1_b + (long)i * kE, q, qbf);
    // FFN
    mgemm<128>(stream, qbf, 0, kE, f1T_i, 256, 256, 1, ffn_b1 + (long)i * kFF,
               nullptr, hid_bf, kFF, kNQ, 4, kFF, 1);
    mgemm<64>(stream, hid_bf, 0, kFF, f2T_i, 512, 512, 1,
              ffn_b2 + (long)i * kE, tmp, nullptr, kE, kNQ, 4, kE, 0);
    ln_res_kernel<<<kNQ / 4, 256, 0, stream>>>(q, tmp, ln2_g + (long)i * kE,
                                               ln2_b + (long)i * kE, q, qbf);
  }

  transpose_kernel<<<dim3(kE / 32, kNQ / 32), 256, 0, stream>>>(q,
                                                                (float*)d_out);
}

// Round 4
// 1337.568 us; speedup vs baseline: 2.9262x; 1.2955x over previous
//
#include <hip/hip_runtime.h>
#include <hip/hip_bf16.h>
#include <stdint.h>

// Problem constants
static constexpr int kL  = 5;
static constexpr int kNH = 4;
static constexpr int kP  = 4;
static constexpr int kE  = 256;
static constexpr int kC  = 256;
static constexpr int kH  = 128;
static constexpr int kW  = 128;
static constexpr int kNQ = kH * kW;          // 16384
static constexpr int kNL = 6;
static constexpr int kFF = 2 * kE;           // 512
static constexpr int kCOMB = 240;            // 160 off + 80 aw

typedef short bf16x8 __attribute__((ext_vector_type(8)));
typedef float f32x4 __attribute__((ext_vector_type(4)));

__device__ __forceinline__ short f2bf(float x) {
  union { float f; uint32_t u; } v; v.f = x;
  uint32_t r = v.u + 0x7fffu + ((v.u >> 16) & 1u);
  return (short)(r >> 16);
}

__device__ __forceinline__ void gl_lds16(const void* g, void* l) {
  __builtin_amdgcn_global_load_lds(
      (const __attribute__((address_space(1))) void*)g,
      (__attribute__((address_space(3))) void*)l, 16, 0, 0);
}

// ---------------------------------------------------------------------------
// bf16 MFMA GEMM: C = sum_bb A[bb] @ B^T + bias  (B stored transposed [N,K])
// Block tile: 128 rows x BN cols. 4 waves in 2x2 grid; NTW = BN/32 col tiles
// per wave -> full coverage.
// ---------------------------------------------------------------------------
template <int BN>
__global__ __launch_bounds__(256) void mfma_gemm_kernel(
    const short* __restrict__ A, long sAb, int lda,
    const short* __restrict__ BT, int ldbt, int Kb, int nbatch,
    const float* __restrict__ bias,
    float* __restrict__ Cf, short* __restrict__ Cb, int ldc,
    int Nreal, int relu) {
  constexpr int NTW = BN / 32;         // col tiles per wave
  __shared__ short As[128 * 32];
  __shared__ short Bs[BN * 32];
  const int tid = threadIdx.x;
  const int wave = tid >> 6, lane = tid & 63;
  const int wy = wave >> 1, wx = wave & 1;   // 2x2 wave grid
  const long row0 = (long)blockIdx.y * 128;
  const int col0 = blockIdx.x * BN;
  const int srow = lane >> 2;          // 0..15
  const int skof = (lane & 3) * 8;     // element offset within 32-elem k row
  const int fr = lane & 15;
  const int fq = lane >> 4;
  f32x4 acc[4][NTW] = {};
  for (int bb = 0; bb < nbatch; ++bb) {
    const short* Ab = A + (long)bb * sAb + row0 * lda;
    const short* Bb = BT + (long)col0 * ldbt + (long)bb * Kb;
    for (int k0 = 0; k0 < Kb; k0 += 32) {
      __syncthreads();
#pragma unroll
      for (int j = 0; j < 2; ++j) {          // A: 8 insts x 16 rows = 128
        int inst = wave * 2 + j;
        int r = inst * 16 + srow;
        gl_lds16(Ab + (long)r * lda + k0 + skof, &As[inst * 512]);
      }
#pragma unroll
      for (int j = 0; j < BN / 64; ++j) {    // B: BN/16 insts x 16 rows
        int inst = wave * (BN / 64) + j;
        int r = inst * 16 + srow;
        gl_lds16(Bb + (long)r * ldbt + k0 + skof, &Bs[inst * 512]);
      }
      __syncthreads();
      bf16x8 af[4], bfv[NTW];
#pragma unroll
      for (int t = 0; t < 4; ++t)
        af[t] = *(const bf16x8*)&As[(wy * 64 + t * 16 + fr) * 32 + fq * 8];
#pragma unroll
      for (int t = 0; t < NTW; ++t)
        bfv[t] = *(const bf16x8*)&Bs[(wx * (BN / 2) + t * 16 + fr) * 32 + fq * 8];
#pragma unroll
      for (int mt = 0; mt < 4; ++mt)
#pragma unroll
        for (int nt = 0; nt < NTW; ++nt)
          acc[mt][nt] = __builtin_amdgcn_mfma_f32_16x16x32_bf16(
              af[mt], bfv[nt], acc[mt][nt], 0, 0, 0);
    }
  }
  const int ccol0 = col0 + wx * (BN / 2) + fr;
  const long crow0 = row0 + wy * 64 + fq * 4;
#pragma unroll
  for (int nt = 0; nt < NTW; ++nt) {
    int col = ccol0 + nt * 16;
    bool cok = col < Nreal;
    float bv = (cok && bias) ? bias[col] : 0.f;
#pragma unroll
    for (int mt = 0; mt < 4; ++mt) {
#pragma unroll
      for (int r = 0; r < 4; ++r) {
        long row = crow0 + mt * 16 + r;
        float v = acc[mt][nt][r] + bv;
        if (relu) v = fmaxf(v, 0.f);
        if (cok) {
          if (Cf) Cf[row * ldc + col] = v;
          if (Cb) Cb[row * ldc + col] = f2bf(v);
        }
      }
    }
  }
}

// ---------------------------------------------------------------------------
// weight convert+transpose: in fp32 [Z,K,N] -> out bf16 [Z,N,K]
// ---------------------------------------------------------------------------
__global__ __launch_bounds__(256) void wt_convert_kernel(
    const float* __restrict__ in, short* __restrict__ out, int K, int N) {
  long idx = (long)blockIdx.x * 256 + threadIdx.x;  // over N*K
  int z = blockIdx.y;
  int n = (int)(idx / K);
  int k = (int)(idx - (long)n * K);
  out[(long)z * N * K + idx] = f2bf(in[(long)z * K * N + (long)k * N + n]);
}

// off_w [Z,256,160] + aw_w [Z,256,80] -> combT bf16 [Z, 256 rows(n), 256(k)]
__global__ __launch_bounds__(256) void comb_convert_kernel(
    const float* __restrict__ off_w, const float* __restrict__ aw_w,
    const float* __restrict__ off_b, const float* __restrict__ aw_b,
    short* __restrict__ combT, float* __restrict__ comb_bias) {
  int idx = blockIdx.x * 256 + threadIdx.x;   // 65536 per z
  int z = blockIdx.y;
  int n = idx >> 8, k = idx & 255;
  float v = 0.f;
  if (n < 160) v = off_w[((long)z * 256 + k) * 160 + n];
  else if (n < kCOMB) v = aw_w[((long)z * 256 + k) * 80 + (n - 160)];
  combT[(long)z * 65536 + idx] = f2bf(v);
  if (k == 0)
    comb_bias[z * 256 + n] =
        (n < 160) ? off_b[z * 160 + n]
                  : (n < kCOMB ? aw_b[z * 80 + (n - 160)] : 0.f);
}

// ---------------------------------------------------------------------------
// LN over channels of feat [L, C, nq]: stats
// ---------------------------------------------------------------------------
__global__ __launch_bounds__(256) void ln_stats_kernel(
    const float* __restrict__ feat, float* __restrict__ mean_out,
    float* __restrict__ rstd_out) {
  int i = blockIdx.x * 256 + threadIdx.x;
  int l = i >> 14;
  int n = i & (kNQ - 1);
  const float* base = feat + (long)l * kC * kNQ + n;
  float s = 0.f, s2 = 0.f;
  for (int c = 0; c < kC; ++c) {
    float v = base[(long)c * kNQ];
    s += v; s2 += v * v;
  }
  float m = s * (1.f / kC);
  float var = s2 * (1.f / kC) - m * m;
  mean_out[i] = m;
  rstd_out[i] = rsqrtf(var + 1e-5f);
}

// LN apply + transpose -> f bf16 [L, nq, C]
__global__ __launch_bounds__(256) void ln_apply_kernel(
    const float* __restrict__ feat, const float* __restrict__ mean_in,
    const float* __restrict__ rstd_in, const float* __restrict__ g,
    const float* __restrict__ b, short* __restrict__ f) {
  __shared__ float tile[32][33];
  int l  = blockIdx.z;
  int cb = blockIdx.x * 32, nb = blockIdx.y * 32;
  int tx = threadIdx.x & 31;
  int ty = threadIdx.x >> 5;
#pragma unroll
  for (int j = 0; j < 4; ++j) {
    int c = ty + j * 8;
    tile[c][tx] = feat[((long)(l * kC + cb + c)) * kNQ + nb + tx];
  }
  __syncthreads();
#pragma unroll
  for (int j = 0; j < 4; ++j) {
    int nl = ty + j * 8;
    int n  = nb + nl;
    float m  = mean_in[l * kNQ + n];
    float rs = rstd_in[l * kNQ + n];
    int c = cb + tx;
    float v = (tile[tx][nl] - m) * rs * g[l * kC + c] + b[l * kC + c];
    f[((long)l * kNQ + n) * kC + c] = f2bf(v);
  }
}

// qp = bf16(q + pos), pos on the fly (used for layer 0 only)
__global__ __launch_bounds__(256) void qp_kernel(
    const float* __restrict__ q, const float* __restrict__ pos_row,
    const float* __restrict__ pos_col, short* __restrict__ qp) {
  int idx = blockIdx.x * 256 + threadIdx.x;  // over nq*64 (4 elems each)
  int n = idx >> 6;
  int e4 = (idx & 63) * 4;
  int w = n & (kW - 1), h = n >> 7;
  float4 vq = *(const float4*)(q + (long)n * kE + e4);
  float4 vp = (e4 < 128) ? *(const float4*)(pos_col + w * 128 + e4)
                         : *(const float4*)(pos_row + h * 128 + e4 - 128);
  short4 o;
  o.x = f2bf(vq.x + vp.x); o.y = f2bf(vq.y + vp.y);
  o.z = f2bf(vq.z + vp.z); o.w = f2bf(vq.w + vp.w);
  *(short4*)(qp + (long)n * kE + e4) = o;
}

// ---------------------------------------------------------------------------
// Deformable sampling, wave per (n,h). Phase 1: lanes 0..19 do softmax over
// the 20 raw aw scores (shuffle-reduce) and compute 4 corners' (byteoff,coef)
// into LDS. Phase 2: all 64 lanes (lane=channel) do 80 broadcast ds_reads +
// bf16 gathers + FMA. val is bf16 [L, nq, E].
// ---------------------------------------------------------------------------
__global__ __launch_bounds__(256) void sample_kernel(
    const float* __restrict__ comb, const short* __restrict__ val,
    short* __restrict__ accb) {
  __shared__ float2 ic[4][80];
  int wv = threadIdx.x >> 6;
  int lane = threadIdx.x & 63;
  int pair = blockIdx.x * 4 + wv;
  int n = pair >> 2, h = pair & 3;
  int wq = n & (kW - 1);
  int hq = n >> 7;
  // softmax over 20 raw scores (lanes 0..19 hold them; reduce over 32 lanes)
  float raw = (lane < 20) ? comb[(long)n * kCOMB + 160 + h * 20 + lane] : -1e30f;
  float mx = raw;
#pragma unroll
  for (int o = 16; o > 0; o >>= 1) mx = fmaxf(mx, __shfl_xor(mx, o, 32));
  float ev = (lane < 20) ? __expf(raw - mx) : 0.f;
  float se = ev;
#pragma unroll
  for (int o = 16; o > 0; o >>= 1) se += __shfl_xor(se, o, 32);
  if (lane < 20) {
    float awv = ev / se;
    int lp = lane;                     // l*4 + p
    int l = lp >> 2;
    float ox = comb[(long)n * kCOMB + h * 40 + lp * 2 + 0];
    float oy = comb[(long)n * kCOMB + h * 40 + lp * 2 + 1];
    float x = (float)wq + ox;
    float y = (float)hq + oy;
    float x0f = floorf(x), y0f = floorf(y);
    float fx = x - x0f, fy = y - y0f;
    int x0 = (int)x0f, y0 = (int)y0f;
#pragma unroll
    for (int c = 0; c < 4; ++c) {
      int dx = c & 1, dy = c >> 1;
      int ix = x0 + dx, iy = y0 + dy;
      float wgt = (dx ? fx : 1.f - fx) * (dy ? fy : 1.f - fy);
      bool valid = (ix >= 0 && ix < kW && iy >= 0 && iy < kH);
      int cix = min(max(ix, 0), kW - 1);
      int ciy = min(max(iy, 0), kH - 1);
      int sidx = ciy * kW + cix;
      int byteoff = (l * kNQ + sidx) * (kE * 2);   // bf16 row offset
      float coef = valid ? awv * wgt : 0.f;
      ic[wv][lp * 4 + c] = make_float2(__int_as_float(byteoff), coef);
    }
  }
  __syncthreads();
  const char* vb = (const char*)(val + h * 64 + lane);
  float a = 0.f;
#pragma unroll 8
  for (int j = 0; j < 80; ++j) {
    float2 oc = ic[wv][j];
    int off = __float_as_int(oc.x);
    unsigned short u = *(const unsigned short*)(vb + off);
    float v = __uint_as_float((unsigned)u << 16);
    a += oc.y * v;
  }
  accb[(long)n * kE + h * 64 + lane] = f2bf(a);
}

// ---------------------------------------------------------------------------
// q = LayerNorm(a + r) * g + b ; writes fp32 q, optional bf16 copy,
// optional bf16 (q+pos) for the next layer's off/aw GEMM.
// ---------------------------------------------------------------------------
__global__ __launch_bounds__(256) void ln_res_kernel(
    const float* __restrict__ a, const float* __restrict__ r,
    const float* __restrict__ g, const float* __restrict__ b,
    const float* __restrict__ pos_row, const float* __restrict__ pos_col,
    float* __restrict__ out, short* __restrict__ outb,
    short* __restrict__ qp) {
  int wave = threadIdx.x >> 6;
  int lane = threadIdx.x & 63;
  long row = (long)blockIdx.x * 4 + wave;
  float4 va = ((const float4*)(a + row * kE))[lane];
  float4 vr = ((const float4*)(r + row * kE))[lane];
  float x0 = va.x + vr.x, x1 = va.y + vr.y, x2 = va.z + vr.z, x3 = va.w + vr.w;
  float s  = x0 + x1 + x2 + x3;
  float s2 = x0 * x0 + x1 * x1 + x2 * x2 + x3 * x3;
#pragma unroll
  for (int o = 32; o > 0; o >>= 1) {
    s  += __shfl_down(s, o);
    s2 += __shfl_down(s2, o);
  }
  s = __shfl(s, 0); s2 = __shfl(s2, 0);
  float m  = s * (1.f / kE);
  float var = s2 * (1.f / kE) - m * m;
  float rs = rsqrtf(var + 1e-5f);
  float4 vg = ((const float4*)g)[lane];
  float4 vb = ((const float4*)b)[lane];
  float4 o;
  o.x = (x0 - m) * rs * vg.x + vb.x;
  o.y = (x1 - m) * rs * vg.y + vb.y;
  o.z = (x2 - m) * rs * vg.z + vb.z;
  o.w = (x3 - m) * rs * vg.w + vb.w;
  ((float4*)(out + row * kE))[lane] = o;
  if (outb) {
    short4 ob;
    ob.x = f2bf(o.x); ob.y = f2bf(o.y); ob.z = f2bf(o.z); ob.w = f2bf(o.w);
    ((short4*)(outb + row * kE))[lane] = ob;
  }
  if (qp) {
    int w = (int)row & (kW - 1), hh = (int)row >> 7;
    float4 vp = (lane < 32) ? ((const float4*)(pos_col + w * 128))[lane]
                            : ((const float4*)(pos_row + hh * 128))[lane - 32];
    short4 oq;
    oq.x = f2bf(o.x + vp.x); oq.y = f2bf(o.y + vp.y);
    oq.z = f2bf(o.z + vp.z); oq.w = f2bf(o.w + vp.w);
    ((short4*)(qp + row * kE))[lane] = oq;
  }
}

// final transpose: out[e, n] = q[n, e]
__global__ __launch_bounds__(256) void transpose_kernel(
    const float* __restrict__ q, float* __restrict__ out) {
  __shared__ float t[32][33];
  int eb = blockIdx.x * 32, nb = blockIdx.y * 32;
  int tx = threadIdx.x & 31, ty = threadIdx.x >> 5;
#pragma unroll
  for (int j = 0; j < 4; ++j)
    t[ty + j * 8][tx] = q[(long)(nb + ty + j * 8) * kE + eb + tx];
  __syncthreads();
#pragma unroll
  for (int j = 0; j < 4; ++j)
    out[(long)(eb + ty + j * 8) * kNQ + nb + tx] = t[tx][ty + j * 8];
}

// ---------------------------------------------------------------------------
template <int BN>
static inline void mgemm(hipStream_t s, const short* A, long sAb, int lda,
                         const short* BT, int ldbt, int Kb, int nbatch,
                         const float* bias, float* Cf, short* Cb, int ldc,
                         int M, int Ntiles, int Nreal, int relu) {
  mfma_gemm_kernel<BN><<<dim3(Ntiles, M / 128), 256, 0, s>>>(
      A, sAb, lda, BT, ldbt, Kb, nbatch, bias, Cf, Cb, ldc, Nreal, relu);
}

extern "C" void kernel_launch(void* const* d_in, const int* in_sizes, int n_in,
                              void* d_out, int out_size, void* d_ws,
                              size_t ws_size, hipStream_t stream) {
  const float* feat    = (const float*)d_in[0];
  const float* norm0_g = (const float*)d_in[1];
  const float* norm0_b = (const float*)d_in[2];
  const float* in_w    = (const float*)d_in[3];
  const float* in_b    = (const float*)d_in[4];
  const float* pos_row = (const float*)d_in[5];
  const float* pos_col = (const float*)d_in[6];
  const float* off_w   = (const float*)d_in[7];
  const float* off_b   = (const float*)d_in[8];
  const float* aw_w    = (const float*)d_in[9];
  const float* aw_b    = (const float*)d_in[10];
  const float* val_w   = (const float*)d_in[11];
  const float* val_b   = (const float*)d_in[12];
  const float* out_w   = (const float*)d_in[13];
  const float* out_b   = (const float*)d_in[14];
  const float* ln1_g   = (const float*)d_in[15];
  const float* ln1_b   = (const float*)d_in[16];
  const float* ln2_g   = (const float*)d_in[17];
  const float* ln2_b   = (const float*)d_in[18];
  const float* ffn_w1  = (const float*)d_in[19];
  const float* ffn_b1  = (const float*)d_in[20];
  const float* ffn_w2  = (const float*)d_in[21];
  const float* ffn_b2  = (const float*)d_in[22];

  char* p = (char*)d_ws;
  auto alloc = [&](size_t bytes) -> char* {
    char* r = p;
    p += (bytes + 255) & ~(size_t)255;
    return r;
  };
  short* f_bf   = (short*)alloc((size_t)kL * kNQ * kC * 2);
  short* val_bf = (short*)alloc((size_t)kL * kNQ * kE * 2);
  float* q      = (float*)alloc((size_t)kNQ * kE * 4);
  float* tmp    = (float*)alloc((size_t)kNQ * kE * 4);
  short* qbf    = (short*)alloc((size_t)kNQ * kE * 2);
  short* qp_bf  = (short*)alloc((size_t)kNQ * kE * 2);
  short* accb   = (short*)alloc((size_t)kNQ * kE * 2);
  short* hid_bf = (short*)alloc((size_t)kNQ * kFF * 2);
  float* comb   = (float*)alloc((size_t)kNQ * kCOMB * 4);
  float* comb_b = (float*)alloc((size_t)kNL * 256 * 4);
  float* meanb  = (float*)alloc((size_t)kL * kNQ * 4);
  float* rstdb  = (float*)alloc((size_t)kL * kNQ * 4);
  short* inT    = (short*)alloc((size_t)256 * 1280 * 2);
  short* valT   = (short*)alloc((size_t)kNL * 256 * 256 * 2);
  short* outT   = (short*)alloc((size_t)kNL * 256 * 256 * 2);
  short* ffn1T  = (short*)alloc((size_t)kNL * 512 * 256 * 2);
  short* ffn2T  = (short*)alloc((size_t)kNL * 256 * 512 * 2);
  short* combT  = (short*)alloc((size_t)kNL * 256 * 256 * 2);

  // weight conversions (bf16, transposed to [N,K])
  wt_convert_kernel<<<dim3(1280, 1), 256, 0, stream>>>(in_w, inT, 1280, 256);
  wt_convert_kernel<<<dim3(256, kNL), 256, 0, stream>>>(val_w, valT, 256, 256);
  wt_convert_kernel<<<dim3(256, kNL), 256, 0, stream>>>(out_w, outT, 256, 256);
  wt_convert_kernel<<<dim3(512, kNL), 256, 0, stream>>>(ffn_w1, ffn1T, 256, 512);
  wt_convert_kernel<<<dim3(512, kNL), 256, 0, stream>>>(ffn_w2, ffn2T, 512, 256);
  comb_convert_kernel<<<dim3(256, kNL), 256, 0, stream>>>(off_w, aw_w, off_b,
                                                          aw_b, combT, comb_b);

  // feature LN -> f bf16
  ln_stats_kernel<<<kL * kNQ / 256, 256, 0, stream>>>(feat, meanb, rstdb);
  ln_apply_kernel<<<dim3(kC / 32, kNQ / 32, kL), 256, 0, stream>>>(
      feat, meanb, rstdb, norm0_g, norm0_b, f_bf);

  // input proj: q = sum_l f[l] @ in_w[l] + in_b   (K-batched)
  mgemm<64>(stream, f_bf, (long)kNQ * kC, kC, inT, 1280, 256, kL, in_b, q,
            nullptr, kE, kNQ, 4, kE, 0);
  qp_kernel<<<kNQ * 64 / 256, 256, 0, stream>>>(q, pos_row, pos_col, qp_bf);

  for (int i = 0; i < kNL; ++i) {
    const short* combT_i = combT + (long)i * 256 * 256;
    const short* valT_i  = valT + (long)i * 256 * 256;
    const short* outT_i  = outT + (long)i * 256 * 256;
    const short* f1T_i   = ffn1T + (long)i * 512 * 256;
    const short* f2T_i   = ffn2T + (long)i * 256 * 512;

    // fused off+aw GEMM (N=240, padded BT rows to 256) -> raw scores
    mgemm<64>(stream, qp_bf, 0, kE, combT_i, 256, 256, 1, comb_b + i * 256,
              comb, nullptr, kCOMB, kNQ, 4, kCOMB, 0);
    // val[l] = f[l] @ val_w[i] : one GEMM, M = L*nq, bf16 out
    mgemm<128>(stream, f_bf, 0, kC, valT_i, 256, 256, 1,
               val_b + (long)i * kE, nullptr, val_bf, kE, kL * kNQ, 2, kE, 0);
    // fused softmax + coef + sampling
    sample_kernel<<<kNQ * kNH / 4, 256, 0, stream>>>(comb, val_bf, accb);
    // out proj
    mgemm<64>(stream, accb, 0, kE, outT_i, 256, 256, 1, out_b + (long)i * kE,
              tmp, nullptr, kE, kNQ, 4, kE, 0);
    ln_res_kernel<<<kNQ / 4, 256, 0, stream>>>(
        q, tmp, ln1_g + (long)i * kE, ln1_b + (long)i * kE, pos_row, pos_col,
        q, qbf, nullptr);
    // FFN
    mgemm<128>(stream, qbf, 0, kE, f1T_i, 256, 256, 1, ffn_b1 + (long)i * kFF,
               nullptr, hid_bf, kFF, kNQ, 4, kFF, 1);
    mgemm<64>(stream, hid_bf, 0, kFF, f2T_i, 512, 512, 1,
              ffn_b2 + (long)i * kE, tmp, nullptr, kE, kNQ, 4, kE, 0);
    ln_res_kernel<<<kNQ / 4, 256, 0, stream>>>(
        q, tmp, ln2_g + (long)i * kE, ln2_b + (long)i * kE, pos_row, pos_col,
        q, nullptr, (i + 1 < kNL) ? qp_bf : nullptr);
  }

  transpose_kernel<<<dim3(kE / 32, kNQ / 32), 256, 0, stream>>>(q,
                                                                (float*)d_out);
}

// Round 5
// 1245.908 us; speedup vs baseline: 3.1415x; 1.0736x over previous
//
#include <hip/hip_runtime.h>
#include <hip/hip_bf16.h>
#include <stdint.h>

// Problem constants
static constexpr int kL  = 5;
static constexpr int kNH = 4;
static constexpr int kP  = 4;
static constexpr int kE  = 256;
static constexpr int kC  = 256;
static constexpr int kH  = 128;
static constexpr int kW  = 128;
static constexpr int kNQ = kH * kW;          // 16384
static constexpr int kNL = 6;
static constexpr int kFF = 2 * kE;           // 512
static constexpr int kCOMB = 240;            // 160 off + 80 aw

typedef short bf16x8 __attribute__((ext_vector_type(8)));
typedef float f32x4 __attribute__((ext_vector_type(4)));

__device__ __forceinline__ short f2bf(float x) {
  union { float f; uint32_t u; } v; v.f = x;
  uint32_t r = v.u + 0x7fffu + ((v.u >> 16) & 1u);
  return (short)(r >> 16);
}

__device__ __forceinline__ void gl_lds16(const void* g, void* l) {
  __builtin_amdgcn_global_load_lds(
      (const __attribute__((address_space(1))) void*)g,
      (__attribute__((address_space(3))) void*)l, 16, 0, 0);
}

// ---------------------------------------------------------------------------
// bf16 MFMA GEMM: C = sum_bb A[bb] @ B^T + bias  (B stored transposed [N,K])
// Block tile: 128 rows x BN cols. 4 waves in 2x2 grid; NTW = BN/32 col tiles
// per wave -> full coverage.
// ---------------------------------------------------------------------------
template <int BN>
__global__ __launch_bounds__(256) void mfma_gemm_kernel(
    const short* __restrict__ A, long sAb, int lda,
    const short* __restrict__ BT, int ldbt, int Kb, int nbatch,
    const float* __restrict__ bias,
    float* __restrict__ Cf, short* __restrict__ Cb, int ldc,
    int Nreal, int relu) {
  constexpr int NTW = BN / 32;         // col tiles per wave
  __shared__ short As[128 * 32];
  __shared__ short Bs[BN * 32];
  const int tid = threadIdx.x;
  const int wave = tid >> 6, lane = tid & 63;
  const int wy = wave >> 1, wx = wave & 1;   // 2x2 wave grid
  const long row0 = (long)blockIdx.y * 128;
  const int col0 = blockIdx.x * BN;
  const int srow = lane >> 2;          // 0..15
  const int skof = (lane & 3) * 8;     // element offset within 32-elem k row
  const int fr = lane & 15;
  const int fq = lane >> 4;
  f32x4 acc[4][NTW] = {};
  for (int bb = 0; bb < nbatch; ++bb) {
    const short* Ab = A + (long)bb * sAb + row0 * lda;
    const short* Bb = BT + (long)col0 * ldbt + (long)bb * Kb;
    for (int k0 = 0; k0 < Kb; k0 += 32) {
      __syncthreads();
#pragma unroll
      for (int j = 0; j < 2; ++j) {          // A: 8 insts x 16 rows = 128
        int inst = wave * 2 + j;
        int r = inst * 16 + srow;
        gl_lds16(Ab + (long)r * lda + k0 + skof, &As[inst * 512]);
      }
#pragma unroll
      for (int j = 0; j < BN / 64; ++j) {    // B: BN/16 insts x 16 rows
        int inst = wave * (BN / 64) + j;
        int r = inst * 16 + srow;
        gl_lds16(Bb + (long)r * ldbt + k0 + skof, &Bs[inst * 512]);
      }
      __syncthreads();
      bf16x8 af[4], bfv[NTW];
#pragma unroll
      for (int t = 0; t < 4; ++t)
        af[t] = *(const bf16x8*)&As[(wy * 64 + t * 16 + fr) * 32 + fq * 8];
#pragma unroll
      for (int t = 0; t < NTW; ++t)
        bfv[t] = *(const bf16x8*)&Bs[(wx * (BN / 2) + t * 16 + fr) * 32 + fq * 8];
#pragma unroll
      for (int mt = 0; mt < 4; ++mt)
#pragma unroll
        for (int nt = 0; nt < NTW; ++nt)
          acc[mt][nt] = __builtin_amdgcn_mfma_f32_16x16x32_bf16(
              af[mt], bfv[nt], acc[mt][nt], 0, 0, 0);
    }
  }
  const int ccol0 = col0 + wx * (BN / 2) + fr;
  const long crow0 = row0 + wy * 64 + fq * 4;
#pragma unroll
  for (int nt = 0; nt < NTW; ++nt) {
    int col = ccol0 + nt * 16;
    bool cok = col < Nreal;
    float bv = (cok && bias) ? bias[col] : 0.f;
#pragma unroll
    for (int mt = 0; mt < 4; ++mt) {
#pragma unroll
      for (int r = 0; r < 4; ++r) {
        long row = crow0 + mt * 16 + r;
        float v = acc[mt][nt][r] + bv;
        if (relu) v = fmaxf(v, 0.f);
        if (cok) {
          if (Cf) Cf[row * ldc + col] = v;
          if (Cb) Cb[row * ldc + col] = f2bf(v);
        }
      }
    }
  }
}

// ---------------------------------------------------------------------------
// weight convert+transpose: in fp32 [Z,K,N] -> out bf16 [Z,N,K]
// ---------------------------------------------------------------------------
__global__ __launch_bounds__(256) void wt_convert_kernel(
    const float* __restrict__ in, short* __restrict__ out, int K, int N) {
  long idx = (long)blockIdx.x * 256 + threadIdx.x;  // over N*K
  int z = blockIdx.y;
  int n = (int)(idx / K);
  int k = (int)(idx - (long)n * K);
  out[(long)z * N * K + idx] = f2bf(in[(long)z * K * N + (long)k * N + n]);
}

// off_w [Z,256,160] + aw_w [Z,256,80] -> combT bf16 [Z, 256 rows(n), 256(k)]
__global__ __launch_bounds__(256) void comb_convert_kernel(
    const float* __restrict__ off_w, const float* __restrict__ aw_w,
    const float* __restrict__ off_b, const float* __restrict__ aw_b,
    short* __restrict__ combT, float* __restrict__ comb_bias) {
  int idx = blockIdx.x * 256 + threadIdx.x;   // 65536 per z
  int z = blockIdx.y;
  int n = idx >> 8, k = idx & 255;
  float v = 0.f;
  if (n < 160) v = off_w[((long)z * 256 + k) * 160 + n];
  else if (n < kCOMB) v = aw_w[((long)z * 256 + k) * 80 + (n - 160)];
  combT[(long)z * 65536 + idx] = f2bf(v);
  if (k == 0)
    comb_bias[z * 256 + n] =
        (n < 160) ? off_b[z * 160 + n]
                  : (n < kCOMB ? aw_b[z * 80 + (n - 160)] : 0.f);
}

// ---------------------------------------------------------------------------
// LN over channels of feat [L, C, nq]: stats
// ---------------------------------------------------------------------------
__global__ __launch_bounds__(256) void ln_stats_kernel(
    const float* __restrict__ feat, float* __restrict__ mean_out,
    float* __restrict__ rstd_out) {
  int i = blockIdx.x * 256 + threadIdx.x;
  int l = i >> 14;
  int n = i & (kNQ - 1);
  const float* base = feat + (long)l * kC * kNQ + n;
  float s = 0.f, s2 = 0.f;
  for (int c = 0; c < kC; ++c) {
    float v = base[(long)c * kNQ];
    s += v; s2 += v * v;
  }
  float m = s * (1.f / kC);
  float var = s2 * (1.f / kC) - m * m;
  mean_out[i] = m;
  rstd_out[i] = rsqrtf(var + 1e-5f);
}

// LN apply + transpose -> f bf16 [L, nq, C]
__global__ __launch_bounds__(256) void ln_apply_kernel(
    const float* __restrict__ feat, const float* __restrict__ mean_in,
    const float* __restrict__ rstd_in, const float* __restrict__ g,
    const float* __restrict__ b, short* __restrict__ f) {
  __shared__ float tile[32][33];
  int l  = blockIdx.z;
  int cb = blockIdx.x * 32, nb = blockIdx.y * 32;
  int tx = threadIdx.x & 31;
  int ty = threadIdx.x >> 5;
#pragma unroll
  for (int j = 0; j < 4; ++j) {
    int c = ty + j * 8;
    tile[c][tx] = feat[((long)(l * kC + cb + c)) * kNQ + nb + tx];
  }
  __syncthreads();
#pragma unroll
  for (int j = 0; j < 4; ++j) {
    int nl = ty + j * 8;
    int n  = nb + nl;
    float m  = mean_in[l * kNQ + n];
    float rs = rstd_in[l * kNQ + n];
    int c = cb + tx;
    float v = (tile[tx][nl] - m) * rs * g[l * kC + c] + b[l * kC + c];
    f[((long)l * kNQ + n) * kC + c] = f2bf(v);
  }
}

// qp = bf16(q + pos), pos on the fly (used after input proj only)
__global__ __launch_bounds__(256) void qp_kernel(
    const float* __restrict__ q, const float* __restrict__ pos_row,
    const float* __restrict__ pos_col, short* __restrict__ qp) {
  int idx = blockIdx.x * 256 + threadIdx.x;  // over nq*64 (4 elems each)
  int n = idx >> 6;
  int e4 = (idx & 63) * 4;
  int w = n & (kW - 1), h = n >> 7;
  float4 vq = *(const float4*)(q + (long)n * kE + e4);
  float4 vp = (e4 < 128) ? *(const float4*)(pos_col + w * 128 + e4)
                         : *(const float4*)(pos_row + h * 128 + e4 - 128);
  short4 o;
  o.x = f2bf(vq.x + vp.x); o.y = f2bf(vq.y + vp.y);
  o.z = f2bf(vq.z + vp.z); o.w = f2bf(vq.w + vp.w);
  *(short4*)(qp + (long)n * kE + e4) = o;
}

// ---------------------------------------------------------------------------
// Deformable sampling, wave per QUERY (all 4 heads).
// Phase 1 (two 32-lane-group passes): softmax over 20 scores per (n,h) +
// 4 corners' (byteoff, coef) -> LDS table ic[wave][head][80] (padded 84).
// Phase 2: lane = (head = lane>>4, channels 4*(lane&15)..+3); 80 iterations
// of broadcast ds_read_b64 + dwordx2 bf16 gather + 4 unpack + 4 FMA.
// val is bf16 [L, nq, E].
// ---------------------------------------------------------------------------
__global__ __launch_bounds__(256) void sample_kernel(
    const float* __restrict__ comb, const short* __restrict__ val,
    short* __restrict__ accb) {
  __shared__ float2 ic[4][4][84];   // [wave][head][lp*4+corner], padded
  int wv = threadIdx.x >> 6;
  int lane = threadIdx.x & 63;
  int n = blockIdx.x * 4 + wv;
  int wq = n & (kW - 1);
  int hq = n >> 7;
  // ---- phase 1: heads (0,1) then (2,3) in 32-lane groups
#pragma unroll
  for (int half = 0; half < 2; ++half) {
    int grp = lane >> 5;             // 0 or 1 within wave
    int lp = lane & 31;              // candidate (l*4+p), valid < 20
    int h = half * 2 + grp;
    float raw = (lp < 20) ? comb[(long)n * kCOMB + 160 + h * 20 + lp] : -1e30f;
    float mx = raw;
#pragma unroll
    for (int o = 16; o > 0; o >>= 1) mx = fmaxf(mx, __shfl_xor(mx, o, 32));
    float ev = (lp < 20) ? __expf(raw - mx) : 0.f;
    float se = ev;
#pragma unroll
    for (int o = 16; o > 0; o >>= 1) se += __shfl_xor(se, o, 32);
    if (lp < 20) {
      float awv = ev / se;
      int l = lp >> 2;
      float ox = comb[(long)n * kCOMB + h * 40 + lp * 2 + 0];
      float oy = comb[(long)n * kCOMB + h * 40 + lp * 2 + 1];
      float x = (float)wq + ox;
      float y = (float)hq + oy;
      float x0f = floorf(x), y0f = floorf(y);
      float fx = x - x0f, fy = y - y0f;
      int x0 = (int)x0f, y0 = (int)y0f;
#pragma unroll
      for (int c = 0; c < 4; ++c) {
        int dx = c & 1, dy = c >> 1;
        int ix = x0 + dx, iy = y0 + dy;
        float wgt = (dx ? fx : 1.f - fx) * (dy ? fy : 1.f - fy);
        bool valid = (ix >= 0 && ix < kW && iy >= 0 && iy < kH);
        int cix = min(max(ix, 0), kW - 1);
        int ciy = min(max(iy, 0), kH - 1);
        int sidx = ciy * kW + cix;
        int byteoff = (l * kNQ + sidx) * (kE * 2);   // bf16 row byte offset
        float coef = valid ? awv * wgt : 0.f;
        ic[wv][h][lp * 4 + c] = make_float2(__int_as_float(byteoff), coef);
      }
    }
  }
  __syncthreads();
  // ---- phase 2: gather-accumulate, 4 channels per lane
  int h = lane >> 4;
  int c4 = (lane & 15) * 4;
  const char* vb = (const char*)val + (h * 64 + c4) * 2;
  const float2* icp = &ic[wv][h][0];
  float a0 = 0.f, a1 = 0.f, a2 = 0.f, a3 = 0.f;
#pragma unroll 4
  for (int j = 0; j < 80; ++j) {
    float2 oc = icp[j];
    int off = __float_as_int(oc.x);
    uint2 u = *(const uint2*)(vb + off);
    float cf = oc.y;
    a0 += cf * __uint_as_float(u.x << 16);
    a1 += cf * __uint_as_float(u.x & 0xffff0000u);
    a2 += cf * __uint_as_float(u.y << 16);
    a3 += cf * __uint_as_float(u.y & 0xffff0000u);
  }
  short4 o;
  o.x = f2bf(a0); o.y = f2bf(a1); o.z = f2bf(a2); o.w = f2bf(a3);
  *(short4*)(accb + (long)n * kE + h * 64 + c4) = o;
}

// ---------------------------------------------------------------------------
// q = LayerNorm(a + r) * g + b ; writes fp32 q, optional bf16 copy,
// optional bf16 (q+pos) for the next layer's off/aw GEMM.
// ---------------------------------------------------------------------------
__global__ __launch_bounds__(256) void ln_res_kernel(
    const float* __restrict__ a, const float* __restrict__ r,
    const float* __restrict__ g, const float* __restrict__ b,
    const float* __restrict__ pos_row, const float* __restrict__ pos_col,
    float* __restrict__ out, short* __restrict__ outb,
    short* __restrict__ qp) {
  int wave = threadIdx.x >> 6;
  int lane = threadIdx.x & 63;
  long row = (long)blockIdx.x * 4 + wave;
  float4 va = ((const float4*)(a + row * kE))[lane];
  float4 vr = ((const float4*)(r + row * kE))[lane];
  float x0 = va.x + vr.x, x1 = va.y + vr.y, x2 = va.z + vr.z, x3 = va.w + vr.w;
  float s  = x0 + x1 + x2 + x3;
  float s2 = x0 * x0 + x1 * x1 + x2 * x2 + x3 * x3;
#pragma unroll
  for (int o = 32; o > 0; o >>= 1) {
    s  += __shfl_down(s, o);
    s2 += __shfl_down(s2, o);
  }
  s = __shfl(s, 0); s2 = __shfl(s2, 0);
  float m  = s * (1.f / kE);
  float var = s2 * (1.f / kE) - m * m;
  float rs = rsqrtf(var + 1e-5f);
  float4 vg = ((const float4*)g)[lane];
  float4 vb = ((const float4*)b)[lane];
  float4 o;
  o.x = (x0 - m) * rs * vg.x + vb.x;
  o.y = (x1 - m) * rs * vg.y + vb.y;
  o.z = (x2 - m) * rs * vg.z + vb.z;
  o.w = (x3 - m) * rs * vg.w + vb.w;
  ((float4*)(out + row * kE))[lane] = o;
  if (outb) {
    short4 ob;
    ob.x = f2bf(o.x); ob.y = f2bf(o.y); ob.z = f2bf(o.z); ob.w = f2bf(o.w);
    ((short4*)(outb + row * kE))[lane] = ob;
  }
  if (qp) {
    int w = (int)row & (kW - 1), hh = (int)row >> 7;
    float4 vp = (lane < 32) ? ((const float4*)(pos_col + w * 128))[lane]
                            : ((const float4*)(pos_row + hh * 128))[lane - 32];
    short4 oq;
    oq.x = f2bf(o.x + vp.x); oq.y = f2bf(o.y + vp.y);
    oq.z = f2bf(o.z + vp.z); oq.w = f2bf(o.w + vp.w);
    ((short4*)(qp + row * kE))[lane] = oq;
  }
}

// final transpose: out[e, n] = q[n, e]
__global__ __launch_bounds__(256) void transpose_kernel(
    const float* __restrict__ q, float* __restrict__ out) {
  __shared__ float t[32][33];
  int eb = blockIdx.x * 32, nb = blockIdx.y * 32;
  int tx = threadIdx.x & 31, ty = threadIdx.x >> 5;
#pragma unroll
  for (int j = 0; j < 4; ++j)
    t[ty + j * 8][tx] = q[(long)(nb + ty + j * 8) * kE + eb + tx];
  __syncthreads();
#pragma unroll
  for (int j = 0; j < 4; ++j)
    out[(long)(eb + ty + j * 8) * kNQ + nb + tx] = t[tx][ty + j * 8];
}

// ---------------------------------------------------------------------------
template <int BN>
static inline void mgemm(hipStream_t s, const short* A, long sAb, int lda,
                         const short* BT, int ldbt, int Kb, int nbatch,
                         const float* bias, float* Cf, short* Cb, int ldc,
                         int M, int Ntiles, int Nreal, int relu) {
  mfma_gemm_kernel<BN><<<dim3(Ntiles, M / 128), 256, 0, s>>>(
      A, sAb, lda, BT, ldbt, Kb, nbatch, bias, Cf, Cb, ldc, Nreal, relu);
}

extern "C" void kernel_launch(void* const* d_in, const int* in_sizes, int n_in,
                              void* d_out, int out_size, void* d_ws,
                              size_t ws_size, hipStream_t stream) {
  const float* feat    = (const float*)d_in[0];
  const float* norm0_g = (const float*)d_in[1];
  const float* norm0_b = (const float*)d_in[2];
  const float* in_w    = (const float*)d_in[3];
  const float* in_b    = (const float*)d_in[4];
  const float* pos_row = (const float*)d_in[5];
  const float* pos_col = (const float*)d_in[6];
  const float* off_w   = (const float*)d_in[7];
  const float* off_b   = (const float*)d_in[8];
  const float* aw_w    = (const float*)d_in[9];
  const float* aw_b    = (const float*)d_in[10];
  const float* val_w   = (const float*)d_in[11];
  const float* val_b   = (const float*)d_in[12];
  const float* out_w   = (const float*)d_in[13];
  const float* out_b   = (const float*)d_in[14];
  const float* ln1_g   = (const float*)d_in[15];
  const float* ln1_b   = (const float*)d_in[16];
  const float* ln2_g   = (const float*)d_in[17];
  const float* ln2_b   = (const float*)d_in[18];
  const float* ffn_w1  = (const float*)d_in[19];
  const float* ffn_b1  = (const float*)d_in[20];
  const float* ffn_w2  = (const float*)d_in[21];
  const float* ffn_b2  = (const float*)d_in[22];

  char* p = (char*)d_ws;
  auto alloc = [&](size_t bytes) -> char* {
    char* r = p;
    p += (bytes + 255) & ~(size_t)255;
    return r;
  };
  short* f_bf   = (short*)alloc((size_t)kL * kNQ * kC * 2);
  short* val_bf = (short*)alloc((size_t)kL * kNQ * kE * 2);
  float* q      = (float*)alloc((size_t)kNQ * kE * 4);
  float* tmp    = (float*)alloc((size_t)kNQ * kE * 4);
  short* qbf    = (short*)alloc((size_t)kNQ * kE * 2);
  short* qp_bf  = (short*)alloc((size_t)kNQ * kE * 2);
  short* accb   = (short*)alloc((size_t)kNQ * kE * 2);
  short* hid_bf = (short*)alloc((size_t)kNQ * kFF * 2);
  float* comb   = (float*)alloc((size_t)kNQ * kCOMB * 4);
  float* comb_b = (float*)alloc((size_t)kNL * 256 * 4);
  float* meanb  = (float*)alloc((size_t)kL * kNQ * 4);
  float* rstdb  = (float*)alloc((size_t)kL * kNQ * 4);
  short* inT    = (short*)alloc((size_t)256 * 1280 * 2);
  short* valT   = (short*)alloc((size_t)kNL * 256 * 256 * 2);
  short* outT   = (short*)alloc((size_t)kNL * 256 * 256 * 2);
  short* ffn1T  = (short*)alloc((size_t)kNL * 512 * 256 * 2);
  short* ffn2T  = (short*)alloc((size_t)kNL * 256 * 512 * 2);
  short* combT  = (short*)alloc((size_t)kNL * 256 * 256 * 2);

  // weight conversions (bf16, transposed to [N,K])
  wt_convert_kernel<<<dim3(1280, 1), 256, 0, stream>>>(in_w, inT, 1280, 256);
  wt_convert_kernel<<<dim3(256, kNL), 256, 0, stream>>>(val_w, valT, 256, 256);
  wt_convert_kernel<<<dim3(256, kNL), 256, 0, stream>>>(out_w, outT, 256, 256);
  wt_convert_kernel<<<dim3(512, kNL), 256, 0, stream>>>(ffn_w1, ffn1T, 256, 512);
  wt_convert_kernel<<<dim3(512, kNL), 256, 0, stream>>>(ffn_w2, ffn2T, 512, 256);
  comb_convert_kernel<<<dim3(256, kNL), 256, 0, stream>>>(off_w, aw_w, off_b,
                                                          aw_b, combT, comb_b);

  // feature LN -> f bf16
  ln_stats_kernel<<<kL * kNQ / 256, 256, 0, stream>>>(feat, meanb, rstdb);
  ln_apply_kernel<<<dim3(kC / 32, kNQ / 32, kL), 256, 0, stream>>>(
      feat, meanb, rstdb, norm0_g, norm0_b, f_bf);

  // input proj: q = sum_l f[l] @ in_w[l] + in_b   (K-batched)
  mgemm<64>(stream, f_bf, (long)kNQ * kC, kC, inT, 1280, 256, kL, in_b, q,
            nullptr, kE, kNQ, 4, kE, 0);
  qp_kernel<<<kNQ * 64 / 256, 256, 0, stream>>>(q, pos_row, pos_col, qp_bf);

  for (int i = 0; i < kNL; ++i) {
    const short* combT_i = combT + (long)i * 256 * 256;
    const short* valT_i  = valT + (long)i * 256 * 256;
    const short* outT_i  = outT + (long)i * 256 * 256;
    const short* f1T_i   = ffn1T + (long)i * 512 * 256;
    const short* f2T_i   = ffn2T + (long)i * 256 * 512;

    // fused off+aw GEMM (N=240, padded BT rows to 256) -> raw scores
    mgemm<64>(stream, qp_bf, 0, kE, combT_i, 256, 256, 1, comb_b + i * 256,
              comb, nullptr, kCOMB, kNQ, 4, kCOMB, 0);
    // val[l] = f[l] @ val_w[i] : one GEMM, M = L*nq, bf16 out
    mgemm<128>(stream, f_bf, 0, kC, valT_i, 256, 256, 1,
               val_b + (long)i * kE, nullptr, val_bf, kE, kL * kNQ, 2, kE, 0);
    // fused softmax + coef + sampling (wave per query)
    sample_kernel<<<kNQ / 4, 256, 0, stream>>>(comb, val_bf, accb);
    // out proj
    mgemm<64>(stream, accb, 0, kE, outT_i, 256, 256, 1, out_b + (long)i * kE,
              tmp, nullptr, kE, kNQ, 4, kE, 0);
    ln_res_kernel<<<kNQ / 4, 256, 0, stream>>>(
        q, tmp, ln1_g + (long)i * kE, ln1_b + (long)i * kE, pos_row, pos_col,
        q, qbf, nullptr);
    // FFN
    mgemm<128>(stream, qbf, 0, kE, f1T_i, 256, 256, 1, ffn_b1 + (long)i * kFF,
               nullptr, hid_bf, kFF, kNQ, 4, kFF, 1);
    mgemm<64>(stream, hid_bf, 0, kFF, f2T_i, 512, 512, 1,
              ffn_b2 + (long)i * kE, tmp, nullptr, kE, kNQ, 4, kE, 0);
    ln_res_kernel<<<kNQ / 4, 256, 0, stream>>>(
        q, tmp, ln2_g + (long)i * kE, ln2_b + (long)i * kE, pos_row, pos_col,
        q, nullptr, (i + 1 < kNL) ? qp_bf : nullptr);
  }

  transpose_kernel<<<dim3(kE / 32, kNQ / 32), 256, 0, stream>>>(q,
                                                                (float*)d_out);
}